// Round 9
// baseline (438.581 us; speedup 1.0000x reference)
//
#include <hip/hip_runtime.h>
#include <hip/hip_fp16.h>

#define IN_F 256
#define OUT_F 256
#define HALF_F 128
#define RPB_SHIFT 9          // 512 rows per bin
#define RPB (1 << RPB_SHIFT)
#define NBINS_MAX 256
#define TILE_E 4096
#define XS_PAD 40            // LDS row stride in bf16 (80 B; 16B-aligned, bank-spread)
#define SHARD_SHIFT 14       // col shard = col >> 14  (8 shards x 16384 source rows)

using bf16x8 = __attribute__((ext_vector_type(8))) short;
using bf16x4 = __attribute__((ext_vector_type(4))) short;
using f32x4  = __attribute__((ext_vector_type(4))) float;
using ull    = unsigned long long;

__device__ inline short bf16rne(float f) {
    unsigned u = __float_as_uint(f);
    u = u + 0x7FFFu + ((u >> 16) & 1u);
    return (short)(u >> 16);
}
__device__ inline unsigned pack_half2(float a, float b) {
    __half2 h = __floats2half2_rn(a, b);
    return *reinterpret_cast<unsigned*>(&h);
}

// ---------------------------------------------------------------------------
// wt[n][k] = bf16(w[k][n])
// ---------------------------------------------------------------------------
__global__ __launch_bounds__(256) void convert_wt_kernel(
    const float* __restrict__ w, short* __restrict__ wt)
{
    const int idx = blockIdx.x * blockDim.x + threadIdx.x;
    const int c = idx >> 8, k = idx & 255;
    wt[(size_t)c * IN_F + k] = bf16rne(w[(size_t)k * OUT_F + c]);
}

// ---------------------------------------------------------------------------
// MFMA GEMM, LDS-staged + double-buffered. BM=32 for occupancy:
// Block 256 thr / 4 waves, tile 32 rows x 256 cols; wave w -> cols w*64..+63.
// acc[2][4] = 32 AGPR/lane. Grid = ceil(M/32) = 3125.
// ---------------------------------------------------------------------------
__global__ __launch_bounds__(256) void mfma_gemm_kernel(
    const float* __restrict__ x, const short* __restrict__ wt,
    __half* __restrict__ supA, __half* __restrict__ supB, int M)
{
    __shared__ short xs[2][32][XS_PAD];

    const int t    = threadIdx.x;
    const int lane = t & 63;
    const int wid  = t >> 6;
    const int l15  = lane & 15;
    const int l4   = lane >> 4;
    const int rowbase = blockIdx.x * 32;
    const int cbase   = wid * 64;

    // staging: thread t -> row t>>3 (0..31), k-offset (t&7)*4
    const int srow = t >> 3;
    const int sks  = (t & 7) * 4;
    int grow = rowbase + srow; if (grow > M - 1) grow = M - 1;
    const float* xsrc = x + (size_t)grow * IN_F + sks;

    f32x4 acc[2][4];
#pragma unroll
    for (int rt = 0; rt < 2; ++rt)
#pragma unroll
        for (int ct = 0; ct < 4; ++ct)
            acc[rt][ct] = (f32x4){0.f, 0.f, 0.f, 0.f};

    const short* wp[4];
#pragma unroll
    for (int ct = 0; ct < 4; ++ct)
        wp[ct] = wt + (size_t)(cbase + ct * 16 + l15) * IN_F + l4 * 8;

    // prologue: stage k0 = 0
    {
        const float4 f = *(const float4*)xsrc;
        bf16x4 v;
        v[0] = bf16rne(f.x); v[1] = bf16rne(f.y);
        v[2] = bf16rne(f.z); v[3] = bf16rne(f.w);
        *(bf16x4*)&xs[0][srow][sks] = v;
    }
    __syncthreads();

#pragma unroll
    for (int k0 = 0; k0 < 8; ++k0) {
        const int cur = k0 & 1;

        float4 nf;
        if (k0 < 7) nf = *(const float4*)(xsrc + (k0 + 1) * 32);

        bf16x8 b[4];
#pragma unroll
        for (int ct = 0; ct < 4; ++ct)
            b[ct] = *(const bf16x8*)(wp[ct] + k0 * 32);

        bf16x8 a[2];
#pragma unroll
        for (int rt = 0; rt < 2; ++rt)
            a[rt] = *(const bf16x8*)&xs[cur][rt * 16 + l15][l4 * 8];

#pragma unroll
        for (int rt = 0; rt < 2; ++rt)
#pragma unroll
            for (int ct = 0; ct < 4; ++ct)
                acc[rt][ct] = __builtin_amdgcn_mfma_f32_16x16x32_bf16(
                    b[ct], a[rt], acc[rt][ct], 0, 0, 0);

        if (k0 < 7) {
            bf16x4 v;
            v[0] = bf16rne(nf.x); v[1] = bf16rne(nf.y);
            v[2] = bf16rne(nf.z); v[3] = bf16rne(nf.w);
            *(bf16x4*)&xs[cur ^ 1][srow][sks] = v;
        }
        __syncthreads();
    }

    __half* dst = (wid < 2) ? supA : supB;
    const int fbase = (wid & 1) * 64;
#pragma unroll
    for (int rt = 0; rt < 2; ++rt) {
        const int r = rowbase + rt * 16 + l15;
        if (r >= M) continue;
#pragma unroll
        for (int ct = 0; ct < 4; ++ct) {
            uint2 pk;
            pk.x = pack_half2(acc[rt][ct][0], acc[rt][ct][1]);
            pk.y = pack_half2(acc[rt][ct][2], acc[rt][ct][3]);
            *(uint2*)(dst + (size_t)r * HALF_F + fbase + ct * 16 + l4 * 4) = pk;
        }
    }
}

// ---------------------------------------------------------------------------
// a1a: per-tile bin histogram -> thist[t][b]   (LDS atomics only)
// ---------------------------------------------------------------------------
__global__ __launch_bounds__(256) void a1a_hist_kernel(
    const int* __restrict__ ei, int* __restrict__ thist, int E)
{
    __shared__ int hist[NBINS_MAX];
    const int tid = threadIdx.x;
    hist[tid] = 0;
    __syncthreads();
    const int base = blockIdx.x * TILE_E;
#pragma unroll
    for (int i = 0; i < TILE_E / 256; ++i) {
        const int e = base + i * 256 + tid;
        if (e < E)
            atomicAdd(&hist[__builtin_nontemporal_load(ei + e) >> RPB_SHIFT], 1);
    }
    __syncthreads();
    thist[(size_t)blockIdx.x * NBINS_MAX + tid] = hist[tid];
}

// per-bin exclusive scan over tiles, in place; also emits btot[b]
__global__ __launch_bounds__(256) void tile_scan_kernel(
    int* __restrict__ thist, int* __restrict__ btot, int T)
{
    const int b   = blockIdx.x;
    const int tid = threadIdx.x;
    __shared__ int s[256];
    int carry = 0;
    for (int c0 = 0; c0 < T; c0 += 256) {
        const int t = c0 + tid;
        const int v = (t < T) ? thist[(size_t)t * NBINS_MAX + b] : 0;
        s[tid] = v;
        __syncthreads();
        for (int d = 1; d < 256; d <<= 1) {
            const int u = (tid >= d) ? s[tid - d] : 0;
            __syncthreads();
            s[tid] += u;
            __syncthreads();
        }
        const int total = s[255];
        if (t < T) thist[(size_t)t * NBINS_MAX + b] = carry + s[tid] - v;
        carry += total;
        __syncthreads();
    }
    if (tid == 0) btot[b] = carry;
}

// exclusive scan of bin totals (1 block)
__global__ __launch_bounds__(NBINS_MAX) void bin_scan_kernel(
    const int* __restrict__ btot, int* __restrict__ bstart, int nbins)
{
    __shared__ int s[NBINS_MAX];
    const int tid = threadIdx.x;
    const int v = (tid < nbins) ? btot[tid] : 0;
    s[tid] = v;
    __syncthreads();
    for (int d = 1; d < NBINS_MAX; d <<= 1) {
        const int u = (tid >= d) ? s[tid - d] : 0;
        __syncthreads();
        s[tid] += u;
        __syncthreads();
    }
    bstart[tid] = s[tid] - v;
}

// ---------------------------------------------------------------------------
// a1b: deterministic binned scatter. pos = bstart[b] + thist[t][b] + LDS-rank.
// Entry = (w:32 | col:17 | rowLo:9)
// ---------------------------------------------------------------------------
__global__ __launch_bounds__(256) void a1b_scatter_kernel(
    const int* __restrict__ ei, const float* __restrict__ ew,
    const int* __restrict__ bstart, const int* __restrict__ thist,
    ull* __restrict__ tscw, int E)
{
    __shared__ int hist[NBINS_MAX];
    __shared__ int rbase[NBINS_MAX];
    const int tid = threadIdx.x;
    hist[tid]  = 0;
    rbase[tid] = bstart[tid] + thist[(size_t)blockIdx.x * NBINS_MAX + tid];
    __syncthreads();
    const int base = blockIdx.x * TILE_E;
#pragma unroll
    for (int i = 0; i < TILE_E / 256; ++i) {
        const int e = base + i * 256 + tid;
        if (e < E) {
            const int      row = __builtin_nontemporal_load(ei + e);
            const int      col = __builtin_nontemporal_load(ei + E + e);
            const unsigned wb  = __builtin_nontemporal_load((const unsigned*)ew + e);
            const int b   = row >> RPB_SHIFT;
            const int rnk = atomicAdd(&hist[b], 1);
            tscw[rbase[b] + rnk] = ((ull)wb << 32) |
                                   ((unsigned)col << RPB_SHIFT) |
                                   (unsigned)(row & (RPB - 1));
        }
    }
}

// ---------------------------------------------------------------------------
// a2: in-bin LDS counting sort by (rowLo:9 | col-shard:3) -> segments are
// row-grouped AND shard-ordered within each row (pull sweeps col space in
// lockstep across waves -> instantaneous gather window ~1 shard ~4 MB).
// Emits counts[row], cursor[row] (= segment start), scw. No global atomics.
// ---------------------------------------------------------------------------
__global__ __launch_bounds__(256) void a2_sort_kernel(
    const ull* __restrict__ tscw, const int* __restrict__ bstart,
    const int* __restrict__ btot, int* __restrict__ counts,
    int* __restrict__ cursor, ull* __restrict__ scw, int M)
{
    const int b   = blockIdx.x;
    const int tid = threadIdx.x;
    const int n   = btot[b];
    const int s0  = bstart[b];

    __shared__ int hcur[RPB * 8];    // hist, then live cursors (4096)
    __shared__ int hbase[RPB * 8];   // scanned bases, bin-relative (4096)
    __shared__ int s[256];

#pragma unroll
    for (int k = 0; k < 16; ++k) hcur[tid + k * 256] = 0;
    __syncthreads();

    // key = (rowLo << 3) | (col >> SHARD_SHIFT); col sits at bits 9..25
    for (int i = tid; i < n; i += 256) {
        const ull en = __builtin_nontemporal_load(tscw + s0 + i);
        const int key = ((int)(en & (RPB - 1)) << 3) |
                        (int)((en >> (RPB_SHIFT + SHARD_SHIFT)) & 7u);
        atomicAdd(&hcur[key], 1);
    }
    __syncthreads();

    // serial-16 per thread + 256-wide block scan -> exclusive bases
    int loc[16];
    int run = 0;
#pragma unroll
    for (int k = 0; k < 16; ++k) { loc[k] = hcur[tid * 16 + k]; run += loc[k]; }
    s[tid] = run;
    __syncthreads();
    for (int d = 1; d < 256; d <<= 1) {
        const int u = (tid >= d) ? s[tid - d] : 0;
        __syncthreads();
        s[tid] += u;
        __syncthreads();
    }
    int accum = s[tid] - run;
#pragma unroll
    for (int k = 0; k < 16; ++k) { hbase[tid * 16 + k] = accum; accum += loc[k]; }
    __syncthreads();

    // counts / cursor per row (2 rows per thread; row r spans keys r*8..r*8+7)
    {
        const int r0 = 2 * tid, r1 = r0 + 1;
        const int st0  = hbase[r0 << 3];
        const int st1  = hbase[r1 << 3];
        const int end1 = (r1 == RPB - 1) ? n : hbase[(r1 + 1) << 3];
        const int gr0 = (b << RPB_SHIFT) + r0, gr1 = gr0 + 1;
        if (gr0 < M) { counts[gr0] = st1 - st0;  cursor[gr0] = s0 + st0; }
        if (gr1 < M) { counts[gr1] = end1 - st1; cursor[gr1] = s0 + st1; }
    }
    // live cursors = absolute positions
#pragma unroll
    for (int k = 0; k < 16; ++k) hcur[tid * 16 + k] = s0 + hbase[tid * 16 + k];
    __syncthreads();

    for (int i = tid; i < n; i += 256) {
        const ull en = __builtin_nontemporal_load(tscw + s0 + i);
        const int key = ((int)(en & (RPB - 1)) << 3) |
                        (int)((en >> (RPB_SHIFT + SHARD_SHIFT)) & 7u);
        const int pos = atomicAdd(&hcur[key], 1);
        scw[pos] = (en & 0xFFFFFFFF00000000ull) |
                   (unsigned)((en >> RPB_SHIFT) & 0x1FFFFu);
    }
}

// ---------------------------------------------------------------------------
// Pull, feature-half pass: wave = 2 rows x 32 lanes. (unchanged — segments
// are now shard-ordered internally, code is identical)
// ---------------------------------------------------------------------------
__global__ __launch_bounds__(256) void pull_half_kernel(
    const int* __restrict__ counts, const int* __restrict__ cursor,
    const ull* __restrict__ scw, const __half* __restrict__ suph,
    const float* __restrict__ biash, float* __restrict__ outh, int M)
{
    const int wv  = blockIdx.x * 4 + (threadIdx.x >> 6);
    const int row = wv * 2 + ((threadIdx.x >> 5) & 1);
    if (row >= M) return;
    const int l = threadIdx.x & 31;

    const int cnt   = counts[row];
    const int start = cursor[row];

    float4 acc = *(const float4*)(biash + l * 4);

#define GATHER_FMA_H(pe)                                                      \
    {                                                                         \
        const int   c  = (int)(unsigned)(pe);                                 \
        const float wj = __uint_as_float((unsigned)((pe) >> 32));             \
        const uint2 v = *(const uint2*)(suph + (size_t)c * HALF_F + l * 4);   \
        const float2 f0 = __half22float2(*(const __half2*)&v.x);              \
        const float2 f1 = __half22float2(*(const __half2*)&v.y);              \
        acc.x = fmaf(wj, f0.x, acc.x); acc.y = fmaf(wj, f0.y, acc.y);         \
        acc.z = fmaf(wj, f1.x, acc.z); acc.w = fmaf(wj, f1.y, acc.w);         \
    }

    for (int j0 = 0; j0 < cnt; j0 += 32) {
        ull pr = 0ull;
        if (j0 + l < cnt)
            pr = __builtin_nontemporal_load(scw + start + j0 + l);
        const int m = min(32, cnt - j0);

        int j = 0;
        for (; j + 4 <= m; j += 4) {
            const ull p0 = __shfl(pr, j, 32),     p1 = __shfl(pr, j + 1, 32);
            const ull p2 = __shfl(pr, j + 2, 32), p3 = __shfl(pr, j + 3, 32);
            GATHER_FMA_H(p0); GATHER_FMA_H(p1);
            GATHER_FMA_H(p2); GATHER_FMA_H(p3);
        }
        for (; j < m; ++j) {
            const ull p = __shfl(pr, j, 32);
            GATHER_FMA_H(p);
        }
    }
#undef GATHER_FMA_H

    f32x4 o; o[0] = acc.x; o[1] = acc.y; o[2] = acc.z; o[3] = acc.w;
    __builtin_nontemporal_store(o, (f32x4*)(outh + (size_t)row * OUT_F + l * 4));
}

// --------------------------- fallback path ---------------------------
__global__ __launch_bounds__(256) void bias_init_kernel(
    float* __restrict__ out, const float* __restrict__ bias, int total4)
{
    const float4* b4 = (const float4*)bias;
    float4* o4 = (float4*)out;
    for (int i = blockIdx.x * blockDim.x + threadIdx.x; i < total4;
         i += gridDim.x * blockDim.x)
        o4[i] = b4[i & 63];
}

__global__ __launch_bounds__(256) void edge_scatter_kernel(
    const int* __restrict__ ei, const float* __restrict__ ew,
    const __half* __restrict__ supA, const __half* __restrict__ supB,
    float* __restrict__ out, int E)
{
    const int e = blockIdx.x * 4 + (threadIdx.x >> 6);
    if (e >= E) return;
    const int lane = threadIdx.x & 63;
    const int   row = ei[e];
    const int   col = ei[E + e];
    const float wgt = ew[e];
    const __half* src = (lane < 32) ? supA : supB;
    const int fl = (lane & 31) * 4;
    const uint2 v = *(const uint2*)(src + (size_t)col * HALF_F + fl);
    const float2 f0 = __half22float2(*(const __half2*)&v.x);
    const float2 f1 = __half22float2(*(const __half2*)&v.y);
    float* o = out + (size_t)row * OUT_F + (lane >> 5) * HALF_F + fl;
    unsafeAtomicAdd(o + 0, wgt * f0.x);
    unsafeAtomicAdd(o + 1, wgt * f0.y);
    unsafeAtomicAdd(o + 2, wgt * f1.x);
    unsafeAtomicAdd(o + 3, wgt * f1.y);
}

// ---------------------------------------------------------------------------
extern "C" void kernel_launch(void* const* d_in, const int* in_sizes, int n_in,
                              void* d_out, int out_size, void* d_ws, size_t ws_size,
                              hipStream_t stream)
{
    const float* x    = (const float*)d_in[0];
    const int*   ei   = (const int*)d_in[1];
    const float* ew   = (const float*)d_in[2];
    const float* w    = (const float*)d_in[3];
    const float* bias = (const float*)d_in[4];
    float* out = (float*)d_out;

    const int M = in_sizes[0] / IN_F;   // 100000
    const int E = in_sizes[2];          // 3,200,000
    const int nbins = (M + RPB - 1) >> RPB_SHIFT;        // 196
    const int T     = (E + TILE_E - 1) / TILE_E;         // 782

    // workspace: supA | supB | counts | btot | cursor | bstart | thist | scw | tscw | wt
    char* p = (char*)d_ws;
    const size_t suph_b   = (((size_t)M * HALF_F * sizeof(__half)) + 255) & ~255ull;
    const size_t counts_b = ((size_t)M * 4 + 255) & ~255ull;
    const size_t btot_b   = NBINS_MAX * 4;
    const size_t cursor_b = counts_b;
    const size_t bstart_b = NBINS_MAX * 4;
    const size_t thist_b  = (((size_t)T * NBINS_MAX * 4) + 255) & ~255ull;
    const size_t scw_b    = ((size_t)E * 8 + 255) & ~255ull;
    const size_t tscw_b   = scw_b;
    const size_t wt_b     = (size_t)IN_F * OUT_F * sizeof(short);
    const size_t need     = 2 * suph_b + counts_b + btot_b + cursor_b + bstart_b
                          + thist_b + scw_b + tscw_b + wt_b;

    __half* supA   = (__half*)p;               p += suph_b;
    __half* supB   = (__half*)p;               p += suph_b;
    int*    counts = (int*)p;                  p += counts_b;
    int*    btot   = (int*)p;                  p += btot_b;
    int*    cursor = (int*)p;                  p += cursor_b;
    int*    bstart = (int*)p;                  p += bstart_b;
    int*    thist  = (int*)p;                  p += thist_b;
    ull*    scw    = (ull*)p;                  p += scw_b;
    ull*    tscw   = (ull*)p;                  p += tscw_b;
    short*  wtb    = (short*)p;

    // 1) wt = bf16(w^T); supA/B = fp16(x @ W) via LDS-staged MFMA (BM=32)
    convert_wt_kernel<<<(IN_F * OUT_F) / 256, 256, 0, stream>>>(w, wtb);
    mfma_gemm_kernel<<<(M + 31) / 32, 256, 0, stream>>>(x, wtb, supA, supB, M);

    if (ws_size >= need) {
        // 2) CSR build: hist -> scans -> binned scatter -> in-bin (row,shard) sort
        a1a_hist_kernel<<<T, 256, 0, stream>>>(ei, thist, E);
        tile_scan_kernel<<<nbins, 256, 0, stream>>>(thist, btot, T);
        bin_scan_kernel<<<1, NBINS_MAX, 0, stream>>>(btot, bstart, nbins);
        a1b_scatter_kernel<<<T, 256, 0, stream>>>(ei, ew, bstart, thist, tscw, E);
        a2_sort_kernel<<<nbins, 256, 0, stream>>>(
            tscw, bstart, btot, counts, cursor, scw, M);
        // 3) pull, two feature-half passes (shard-ordered segments)
        const int pblocks = ((M + 1) / 2 + 3) / 4;
        pull_half_kernel<<<pblocks, 256, 0, stream>>>(
            counts, cursor, scw, supA, bias, out, M);
        pull_half_kernel<<<pblocks, 256, 0, stream>>>(
            counts, cursor, scw, supB, bias + HALF_F, out + HALF_F, M);
    } else {
        const int total4 = M * OUT_F / 4;
        bias_init_kernel<<<2048, 256, 0, stream>>>(out, bias, total4);
        edge_scatter_kernel<<<(E + 3) / 4, 256, 0, stream>>>(ei, ew, supA, supB, out, E);
    }
}